// Round 7
// baseline (1551.493 us; speedup 1.0000x reference)
//
#include <hip/hip_runtime.h>
#include <hip/hip_bf16.h>

// Problem constants: B=128, N=1024, E=16384, ENTITY=100000, EMB=100, HID=100

typedef unsigned int u32;
typedef float f2 __attribute__((ext_vector_type(2)));

__device__ __forceinline__ float bflo(u32 u) {
    union { u32 i; float f; } v; v.i = u << 16; return v.f;
}
__device__ __forceinline__ float bfhi(u32 u) {
    union { u32 i; float f; } v; v.i = u & 0xffff0000u; return v.f;
}
__device__ __forceinline__ u32 f2bf1(float f) {
    union { float f; u32 u; } v; v.f = f;
    return (v.u + 0x7fffu + ((v.u >> 16) & 1u)) >> 16;   // RNE
}
__device__ __forceinline__ u32 packbf(float a, float b) {
    return f2bf1(a) | (f2bf1(b) << 16);
}
__device__ __forceinline__ float sigm(float x) { return 1.f / (1.f + __expf(-x)); }
__device__ __forceinline__ float tanh_fast(float x) {
    float e = __expf(2.f * x);
    return 1.f - 2.f / (e + 1.f);
}

// ---------------------------------------------------------------------------
// Kernel 1: embedding gather + GCN matmul.  support[n][h] (bf16 packed u32)
// ---------------------------------------------------------------------------
__global__ __launch_bounds__(256, 2)
void gcn_kernel(const int* __restrict__ nb, const float* __restrict__ emb,
                const float* __restrict__ w, u32* __restrict__ support)
{
    __shared__ float wl[10000];
    for (int i = threadIdx.x; i < 10000; i += 256) wl[i] = w[i];
    __syncthreads();

    const int n = blockIdx.x * 256 + threadIdx.x;
    const long long row = nb[n];
    const float4* __restrict__ xr = (const float4*)(emb + row * 100);

    float acc[100];
#pragma unroll
    for (int h = 0; h < 100; ++h) acc[h] = 0.f;

    for (int kk = 0; kk < 25; ++kk) {
        const float4 xv = xr[kk];
        const float xs[4] = { xv.x, xv.y, xv.z, xv.w };
#pragma unroll
        for (int q = 0; q < 4; ++q) {
            const float* wrow = &wl[(kk * 4 + q) * 100];
            const float xq = xs[q];
#pragma unroll
            for (int h4 = 0; h4 < 25; ++h4) {
                const float4 w4 = *(const float4*)(wrow + h4 * 4);
                acc[h4*4+0] = fmaf(xq, w4.x, acc[h4*4+0]);
                acc[h4*4+1] = fmaf(xq, w4.y, acc[h4*4+1]);
                acc[h4*4+2] = fmaf(xq, w4.z, acc[h4*4+2]);
                acc[h4*4+3] = fmaf(xq, w4.w, acc[h4*4+3]);
            }
        }
    }

    u32* __restrict__ o = support + (size_t)n * 50;
#pragma unroll
    for (int i = 0; i < 50; ++i) o[i] = packbf(acc[2*i], acc[2*i+1]);
}

// ---------------------------------------------------------------------------
// Kernel 2a: per-sample counting-sort into CSR order.
// ---------------------------------------------------------------------------
__global__ __launch_bounds__(256, 2)
void csr_build(const int* __restrict__ arow, const int* __restrict__ acol,
               const float* __restrict__ aval,
               int* __restrict__ offs, int2* __restrict__ csr)
{
    __shared__ int cnt[1024];
    __shared__ int part[256];
    __shared__ int offl[1024];

    const int b   = blockIdx.x;
    const int tid = threadIdx.x;
    const int*   rw = arow + b * 16384;
    const int*   cl = acol + b * 16384;
    const float* vl = aval + b * 16384;

    for (int i = tid; i < 1024; i += 256) cnt[i] = 0;
    __syncthreads();
    for (int e = tid; e < 16384; e += 256) atomicAdd(&cnt[rw[e]], 1);
    __syncthreads();

    int c[4]; int s = 0;
#pragma unroll
    for (int q = 0; q < 4; ++q) { c[q] = cnt[tid * 4 + q]; s += c[q]; }
    part[tid] = s;
    __syncthreads();
    for (int off = 1; off < 256; off <<= 1) {
        int v = (tid >= off) ? part[tid - off] : 0;
        __syncthreads();
        part[tid] += v;
        __syncthreads();
    }
    int run = part[tid] - s;
#pragma unroll
    for (int q = 0; q < 4; ++q) { offl[tid * 4 + q] = run; run += c[q]; }
    __syncthreads();

    for (int i = tid; i < 1024; i += 256) offs[b * 1025 + i] = offl[i];
    if (tid == 0) offs[b * 1025 + 1024] = 16384;

    int2* cs = csr + (size_t)b * 16384;
    for (int e = tid; e < 16384; e += 256) {
        const int r   = rw[e];
        const int pos = atomicAdd(&offl[r], 1);
        int2 cv; cv.x = cl[e]; cv.y = __float_as_int(vl[e]);
        cs[pos] = cv;
    }
}

// ---------------------------------------------------------------------------
// Kernel 2b: atomic-free CSR aggregate.  50 lanes/row.
// ---------------------------------------------------------------------------
__global__ __launch_bounds__(256, 4)
void spmm_agg(const int* __restrict__ offs, const int2* __restrict__ csr,
              const u32* __restrict__ support,
              const float* __restrict__ gcn_b, u32* __restrict__ seq)
{
    const int b    = blockIdx.y;
    const int lr   = threadIdx.x / 50;
    const int lane = threadIdx.x % 50;
    const int r    = blockIdx.x * 5 + lr;
    if (lr >= 5 || r >= 1024) return;

    const int e0 = offs[b * 1025 + r];
    const int e1 = offs[b * 1025 + r + 1];
    const int2* __restrict__ cs = csr + (size_t)b * 16384;
    const u32* __restrict__ supb = support + (size_t)b * 1024 * 50;

    float a0 = 0.f, a1 = 0.f;
    for (int e = e0; e < e1; ++e) {
        const int2 cv = cs[e];
        const float v = __int_as_float(cv.y);
        const u32 u = supb[(size_t)cv.x * 50 + lane];
        a0 = fmaf(v, bflo(u), a0);
        a1 = fmaf(v, bfhi(u), a1);
    }
    a0 += gcn_b[2 * lane];
    a1 += gcn_b[2 * lane + 1];
    seq[((size_t)b * 1024 + r) * 50 + lane] = packbf(a0, a1);
}

// ---------------------------------------------------------------------------
// Kernel 3: gx GEMM.  gx[m][g*50+jw] packs units (2jw,2jw+1) of gate g, bf16.
// m = b*CT + t (local to the window being computed).
// ---------------------------------------------------------------------------
__global__ __launch_bounds__(256, 2)
void gx_gemm0(const u32* __restrict__ seq, const float* __restrict__ w_ih,
              const float* __restrict__ b_ih, u32* __restrict__ gxW,
              int c0, int ctl, int CT)
{
    __shared__ float wl[10000];
    const int g    = blockIdx.x % 3;
    const int tile = blockIdx.x / 3;
    const int tid  = threadIdx.x;

    for (int i = tid; i < 10000; i += 256)
        wl[(i % 100) * 100 + (i / 100)] = w_ih[g * 10000 + i];   // transpose
    __syncthreads();

    const int m = tile * 256 + tid;              // 0 .. 128*CT-1
    const int b = m >> ctl;
    const int t = m & (CT - 1);
    const uint2* sr2 = (const uint2*)(seq + ((size_t)b * 1024 + c0 + t) * 50);

    float acc[100];
    const float4* bi4 = (const float4*)(b_ih + g * 100);
#pragma unroll
    for (int j4 = 0; j4 < 25; ++j4) {
        const float4 bv = bi4[j4];
        acc[j4*4+0] = bv.x; acc[j4*4+1] = bv.y; acc[j4*4+2] = bv.z; acc[j4*4+3] = bv.w;
    }

    for (int kk = 0; kk < 25; ++kk) {
        const uint2 up = sr2[kk];
        const float xs[4] = { bflo(up.x), bfhi(up.x), bflo(up.y), bfhi(up.y) };
#pragma unroll
        for (int q = 0; q < 4; ++q) {
            const float* wrow = &wl[(kk * 4 + q) * 100];
            const float xq = xs[q];
#pragma unroll
            for (int j4 = 0; j4 < 25; ++j4) {
                const float4 w4 = *(const float4*)(wrow + j4 * 4);
                acc[j4*4+0] = fmaf(xq, w4.x, acc[j4*4+0]);
                acc[j4*4+1] = fmaf(xq, w4.y, acc[j4*4+1]);
                acc[j4*4+2] = fmaf(xq, w4.z, acc[j4*4+2]);
                acc[j4*4+3] = fmaf(xq, w4.w, acc[j4*4+3]);
            }
        }
    }

    u32* og = gxW + (size_t)m * 150 + g * 50;
#pragma unroll
    for (int i = 0; i < 50; ++i) og[i] = packbf(acc[2*i], acc[2*i+1]);
}

// ---------------------------------------------------------------------------
// Kernel 4 (v10): GRU recurrence, 1 sample/block, 1024 threads (16 waves).
// 8 threads per unit j (tid>>3): thread p=tid&7 holds k-groups q=8i+p
// (i=0..3, q>24 masked to zero) = 48 weight floats -> per-thread need ~85
// regs, SMALL enough for the allocator's demonstrated behavior (it granted
// 88 at need 130 and spilled; here it shouldn't need to).  waves_per_eu(4,4)
// pins 1 block/CU (budget 128/wave).
//
// Combine tree is ALL-VALU via DPP (no DS-pipe shfl):
//   xor1 = quad_perm[1,0,3,2] (0xB1), xor2 = quad_perm[2,3,0,1] (0x4E);
//   after those the value is quad-uniform, so the xor4 step can use
//   row_half_mirror (0x141): lane l reads l^7, which lies in the partner
//   quad of its 8-group.  Per-step DS ops drop from ~112 (v8) to ~65
//   (64 conflict-free broadcast h-reads + 1 write).  One barrier/step,
//   h double-buffered padded to 128 (zeros beyond 100), gx prefetch dist 2.
// ---------------------------------------------------------------------------
__global__ __launch_bounds__(1024)
__attribute__((amdgpu_waves_per_eu(4, 4)))
void gru_v10(const u32* __restrict__ gxR, size_t sampStride,
             const float* __restrict__ w_hh, const float* __restrict__ b_hh,
             float* __restrict__ hg, const float* __restrict__ fc1_w,
             const float* __restrict__ fc1_b, float* __restrict__ out,
             int first, int last, int CT)
{
    __shared__ float hb[2][128];        // double-buffered h, [100..127] = 0

    const int tid  = threadIdx.x;
    const int samp = blockIdx.x;
    const int j    = tid >> 3;          // unit 0..127 (meaningful for j<100)
    const int p    = tid & 7;           // k-eighth parity (lane&7)
    const int hi   = j & 1;             // which bf16 half of the gx word
    const int jc   = (j < 100) ? j : 99;   // clamp so ALL loads are valid

    // ---- weights: 4 float4-groups per gate, NAMED f2 scalars --------------
#define WDECL(g) f2 g##0a, g##0b, g##1a, g##1b, g##2a, g##2b, g##3a, g##3b
    WDECL(wr); WDECL(wz); WDECL(wn);
#undef WDECL
    {
        const float* r0 = w_hh + (size_t)jc * 100;
#define WLOAD(i)                                                              \
        {                                                                     \
            const int   q  = 8 * (i) + p;                                     \
            const int   qc = (q < 25) ? q : 24;                               \
            const float mm = (q < 25) ? 1.f : 0.f;                            \
            float4 v;                                                         \
            v = *(const float4*)(r0 + 4 * qc);                                \
            wr##i##a = (f2){v.x * mm, v.y * mm};                              \
            wr##i##b = (f2){v.z * mm, v.w * mm};                              \
            v = *(const float4*)(r0 + 10000 + 4 * qc);                        \
            wz##i##a = (f2){v.x * mm, v.y * mm};                              \
            wz##i##b = (f2){v.z * mm, v.w * mm};                              \
            v = *(const float4*)(r0 + 20000 + 4 * qc);                        \
            wn##i##a = (f2){v.x * mm, v.y * mm};                              \
            wn##i##b = (f2){v.z * mm, v.w * mm};                              \
        }
        WLOAD(0) WLOAD(1) WLOAD(2) WLOAD(3)
#undef WLOAD
    }

    const float bhr = b_hh[jc];
    const float bhz = b_hh[100 + jc];
    const float bhn = b_hh[200 + jc];
    float hreg = first ? 0.f : hg[samp * 100 + jc];

    if (j < 100 && p == 0) hb[0][j] = hreg;
    if (tid >= 100 && tid < 128) { hb[0][tid] = 0.f; hb[1][tid] = 0.f; }
    __syncthreads();

    // gx prefetch, distance 2 (a-regs: even t, b-regs: odd t); clamped base so
    // inactive threads load valid memory.
    const int w50 = ((j >> 1) < 50) ? (j >> 1) : 49;
    const u32* gp = gxR + (size_t)samp * sampStride + w50;
    u32 a0 = gp[0],   a1 = gp[50],  a2 = gp[100];        // t = 0
    u32 b0 = gp[150], b1 = gp[200], b2 = gp[250];        // t = 1

    int cur = 0;

    // DPP reduce-add: dst gets s + s[partner] (all-VALU, no DS pipe)
#define DPPADD(s, CTRL)                                                       \
    (s) += __int_as_float(__builtin_amdgcn_mov_dpp(                           \
               __float_as_int(s), (CTRL), 0xF, 0xF, true))

#define SG(i)                                                                 \
    {                                                                         \
        const float4 hv = *(const float4*)(hc + 32 * (i));                    \
        const f2 h01 = {hv.x, hv.y}, h23 = {hv.z, hv.w};                      \
        ar0 += wr##i##a * h01;  ar1 += wr##i##b * h23;                        \
        az0 += wz##i##a * h01;  az1 += wz##i##b * h23;                        \
        an0 += wn##i##a * h01;  an1 += wn##i##b * h23;                        \
    }

#define GRU_STEP(T, X0, X1, X2)                                               \
    {                                                                         \
        const float* hc = &hb[cur][4 * p];                                    \
        f2 ar0 = {0.f,0.f}, ar1 = {0.f,0.f};                                  \
        f2 az0 = {0.f,0.f}, az1 = {0.f,0.f};                                  \
        f2 an0 = {0.f,0.f}, an1 = {0.f,0.f};                                  \
        SG(0) SG(1) SG(2) SG(3)                                               \
        const u32 c0 = X0, c1 = X1, c2 = X2;                                  \
        if ((T) + 2 < CT) {                                                   \
            const u32* q2 = gp + (size_t)((T) + 2) * 150;                     \
            X0 = q2[0]; X1 = q2[50]; X2 = q2[100];                            \
        }                                                                     \
        float sr = (ar0.x + ar0.y) + (ar1.x + ar1.y);                         \
        float sz = (az0.x + az0.y) + (az1.x + az1.y);                         \
        float sn = (an0.x + an0.y) + (an1.x + an1.y);                         \
        DPPADD(sr, 0xB1);  DPPADD(sz, 0xB1);  DPPADD(sn, 0xB1);               \
        DPPADD(sr, 0x4E);  DPPADD(sz, 0x4E);  DPPADD(sn, 0x4E);               \
        DPPADD(sr, 0x141); DPPADD(sz, 0x141); DPPADD(sn, 0x141);              \
        const float gxr = hi ? bfhi(c0) : bflo(c0);                           \
        const float gxz = hi ? bfhi(c1) : bflo(c1);                           \
        const float gxn = hi ? bfhi(c2) : bflo(c2);                           \
        const float rg  = sigm(gxr + sr + bhr);                               \
        const float zg  = sigm(gxz + sz + bhz);                               \
        const float ng  = tanh_fast(gxn + rg * (sn + bhn));                   \
        hreg = (1.f - zg) * ng + zg * hreg;                                   \
        if (j < 100 && p == 0) hb[cur ^ 1][j] = hreg;                         \
        __syncthreads();                                                      \
        cur ^= 1;                                                             \
    }

    for (int t = 0; t < CT; t += 2) {
        GRU_STEP(t,     a0, a1, a2);
        GRU_STEP(t + 1, b0, b1, b2);
    }
#undef GRU_STEP
#undef SG
#undef DPPADD

    if (j < 100 && p == 0) hg[samp * 100 + j] = hreg;
    if (last && tid < 100) {
        const float* hc = hb[cur];
        const float4* fw = (const float4*)(fc1_w + (size_t)tid * 100);
        float s0 = 0.f, s1 = 0.f, s2 = 0.f, s3 = 0.f;
#pragma unroll
        for (int kk = 0; kk < 25; ++kk) {
            const float4 wv = fw[kk];
            const float4 hv = *(const float4*)(hc + kk * 4);
            s0 = fmaf(wv.x, hv.x, s0);
            s1 = fmaf(wv.y, hv.y, s1);
            s2 = fmaf(wv.z, hv.z, s2);
            s3 = fmaf(wv.w, hv.w, s3);
        }
        const float s = (s0 + s1) + (s2 + s3) + fc1_b[tid];
        out[samp * 100 + tid] = fmaxf(s, 0.f);
    }
}

// ---------------------------------------------------------------------------
extern "C" void kernel_launch(void* const* d_in, const int* in_sizes, int n_in,
                              void* d_out, int out_size, void* d_ws, size_t ws_size,
                              hipStream_t stream)
{
    const int*   neighbors = (const int*)  d_in[0];
    const int*   adj_row   = (const int*)  d_in[1];
    const int*   adj_col   = (const int*)  d_in[2];
    const float* adj_val   = (const float*)d_in[3];
    const float* emb       = (const float*)d_in[4];
    const float* gcn_w     = (const float*)d_in[5];
    const float* gcn_b     = (const float*)d_in[6];
    const float* w_ih      = (const float*)d_in[7];
    const float* w_hh      = (const float*)d_in[8];
    const float* b_ih      = (const float*)d_in[9];
    const float* b_hh      = (const float*)d_in[10];
    const float* fc1_w     = (const float*)d_in[11];
    const float* fc1_b     = (const float*)d_in[12];
    float* out = (float*)d_out;

    char* ws = (char*)d_ws;
    const size_t seq_bytes     = (size_t)128 * 1024 * 50 * 4;    // 26,214,400
    const size_t hg_bytes      = 128 * 100 * 4;                  // 51,200
    const size_t support_bytes = (size_t)128 * 1024 * 50 * 4;    // 26,214,400
    const size_t offs_bytes    = (size_t)128 * 1025 * 4;         // 524,800

    u32*   seq = (u32*)ws;
    float* hg  = (float*)(ws + seq_bytes);
    char*  rest = ws + seq_bytes + hg_bytes;
    const size_t rest_avail = ws_size - seq_bytes - hg_bytes;

    // Phase 1 (both modes): support + CSR live in `rest` (43.5 MB), all dead
    // before any gx is written over the same region.
    u32*  support = (u32*)rest;
    int*  offs    = (int*)(rest + support_bytes);
    int2* csr     = (int2*)(rest + support_bytes + offs_bytes);

    gcn_kernel<<<512, 256, 0, stream>>>(neighbors, emb, gcn_w, support);
    csr_build<<<128, 256, 0, stream>>>(adj_row, adj_col, adj_val, offs, csr);
    spmm_agg<<<dim3(205, 128), 256, 0, stream>>>(offs, csr, support, gcn_b, seq);

    const size_t gx_full = (size_t)128 * 1024 * 150 * 4;         // 78,643,200
    u32* gx = (u32*)rest;

    if (rest_avail >= gx_full) {
        // full-window: one GEMM dispatch, one 1024-step GRU dispatch
        gx_gemm0<<<1536, 256, 0, stream>>>(seq, w_ih, b_ih, gx, 0, 10, 1024);
        gru_v10<<<128, 1024, 0, stream>>>(gx, (size_t)1024 * 150, w_hh, b_hh, hg,
                                          fc1_w, fc1_b, out, 1, 1, 1024);
    } else {
        // chunked fallback
        int CT = 512, ctl = 9;
        while (CT > 8 && (size_t)128 * CT * 150 * 4 > rest_avail) { CT >>= 1; --ctl; }
        const int nch = 1024 / CT;
        for (int c = 0; c < nch; ++c) {
            gx_gemm0<<<3 * (128 * CT / 256), 256, 0, stream>>>(seq, w_ih, b_ih, gx,
                                                               c * CT, ctl, CT);
            gru_v10<<<128, 1024, 0, stream>>>(gx, (size_t)CT * 150, w_hh, b_hh, hg,
                                              fc1_w, fc1_b, out,
                                              (c == 0) ? 1 : 0, (c == nch - 1) ? 1 : 0, CT);
        }
    }
}

// Round 9
// 1166.567 us; speedup vs baseline: 1.3300x; 1.3300x over previous
//
#include <hip/hip_runtime.h>
#include <hip/hip_bf16.h>

// Problem constants: B=128, N=1024, E=16384, ENTITY=100000, EMB=100, HID=100

typedef unsigned int u32;
typedef float f2 __attribute__((ext_vector_type(2)));

__device__ __forceinline__ float bflo(u32 u) {
    union { u32 i; float f; } v; v.i = u << 16; return v.f;
}
__device__ __forceinline__ float bfhi(u32 u) {
    union { u32 i; float f; } v; v.i = u & 0xffff0000u; return v.f;
}
__device__ __forceinline__ u32 f2bf1(float f) {
    union { float f; u32 u; } v; v.f = f;
    return (v.u + 0x7fffu + ((v.u >> 16) & 1u)) >> 16;   // RNE
}
__device__ __forceinline__ u32 packbf(float a, float b) {
    return f2bf1(a) | (f2bf1(b) << 16);
}
__device__ __forceinline__ float sigm(float x) { return 1.f / (1.f + __expf(-x)); }
__device__ __forceinline__ float tanh_fast(float x) {
    float e = __expf(2.f * x);
    return 1.f - 2.f / (e + 1.f);
}

// ---------------------------------------------------------------------------
// Kernel 1: embedding gather + GCN matmul.  support[n][h] (bf16 packed u32)
// ---------------------------------------------------------------------------
__global__ __launch_bounds__(256, 2)
void gcn_kernel(const int* __restrict__ nb, const float* __restrict__ emb,
                const float* __restrict__ w, u32* __restrict__ support)
{
    __shared__ float wl[10000];
    for (int i = threadIdx.x; i < 10000; i += 256) wl[i] = w[i];
    __syncthreads();

    const int n = blockIdx.x * 256 + threadIdx.x;
    const long long row = nb[n];
    const float4* __restrict__ xr = (const float4*)(emb + row * 100);

    float acc[100];
#pragma unroll
    for (int h = 0; h < 100; ++h) acc[h] = 0.f;

    for (int kk = 0; kk < 25; ++kk) {
        const float4 xv = xr[kk];
        const float xs[4] = { xv.x, xv.y, xv.z, xv.w };
#pragma unroll
        for (int q = 0; q < 4; ++q) {
            const float* wrow = &wl[(kk * 4 + q) * 100];
            const float xq = xs[q];
#pragma unroll
            for (int h4 = 0; h4 < 25; ++h4) {
                const float4 w4 = *(const float4*)(wrow + h4 * 4);
                acc[h4*4+0] = fmaf(xq, w4.x, acc[h4*4+0]);
                acc[h4*4+1] = fmaf(xq, w4.y, acc[h4*4+1]);
                acc[h4*4+2] = fmaf(xq, w4.z, acc[h4*4+2]);
                acc[h4*4+3] = fmaf(xq, w4.w, acc[h4*4+3]);
            }
        }
    }

    u32* __restrict__ o = support + (size_t)n * 50;
#pragma unroll
    for (int i = 0; i < 50; ++i) o[i] = packbf(acc[2*i], acc[2*i+1]);
}

// ---------------------------------------------------------------------------
// Kernel 2a: per-sample counting-sort into CSR order.
// ---------------------------------------------------------------------------
__global__ __launch_bounds__(256, 2)
void csr_build(const int* __restrict__ arow, const int* __restrict__ acol,
               const float* __restrict__ aval,
               int* __restrict__ offs, int2* __restrict__ csr)
{
    __shared__ int cnt[1024];
    __shared__ int part[256];
    __shared__ int offl[1024];

    const int b   = blockIdx.x;
    const int tid = threadIdx.x;
    const int*   rw = arow + b * 16384;
    const int*   cl = acol + b * 16384;
    const float* vl = aval + b * 16384;

    for (int i = tid; i < 1024; i += 256) cnt[i] = 0;
    __syncthreads();
    for (int e = tid; e < 16384; e += 256) atomicAdd(&cnt[rw[e]], 1);
    __syncthreads();

    int c[4]; int s = 0;
#pragma unroll
    for (int q = 0; q < 4; ++q) { c[q] = cnt[tid * 4 + q]; s += c[q]; }
    part[tid] = s;
    __syncthreads();
    for (int off = 1; off < 256; off <<= 1) {
        int v = (tid >= off) ? part[tid - off] : 0;
        __syncthreads();
        part[tid] += v;
        __syncthreads();
    }
    int run = part[tid] - s;
#pragma unroll
    for (int q = 0; q < 4; ++q) { offl[tid * 4 + q] = run; run += c[q]; }
    __syncthreads();

    for (int i = tid; i < 1024; i += 256) offs[b * 1025 + i] = offl[i];
    if (tid == 0) offs[b * 1025 + 1024] = 16384;

    int2* cs = csr + (size_t)b * 16384;
    for (int e = tid; e < 16384; e += 256) {
        const int r   = rw[e];
        const int pos = atomicAdd(&offl[r], 1);
        int2 cv; cv.x = cl[e]; cv.y = __float_as_int(vl[e]);
        cs[pos] = cv;
    }
}

// ---------------------------------------------------------------------------
// Kernel 2b: atomic-free CSR aggregate.  50 lanes/row.
// ---------------------------------------------------------------------------
__global__ __launch_bounds__(256, 4)
void spmm_agg(const int* __restrict__ offs, const int2* __restrict__ csr,
              const u32* __restrict__ support,
              const float* __restrict__ gcn_b, u32* __restrict__ seq)
{
    const int b    = blockIdx.y;
    const int lr   = threadIdx.x / 50;
    const int lane = threadIdx.x % 50;
    const int r    = blockIdx.x * 5 + lr;
    if (lr >= 5 || r >= 1024) return;

    const int e0 = offs[b * 1025 + r];
    const int e1 = offs[b * 1025 + r + 1];
    const int2* __restrict__ cs = csr + (size_t)b * 16384;
    const u32* __restrict__ supb = support + (size_t)b * 1024 * 50;

    float a0 = 0.f, a1 = 0.f;
    for (int e = e0; e < e1; ++e) {
        const int2 cv = cs[e];
        const float v = __int_as_float(cv.y);
        const u32 u = supb[(size_t)cv.x * 50 + lane];
        a0 = fmaf(v, bflo(u), a0);
        a1 = fmaf(v, bfhi(u), a1);
    }
    a0 += gcn_b[2 * lane];
    a1 += gcn_b[2 * lane + 1];
    seq[((size_t)b * 1024 + r) * 50 + lane] = packbf(a0, a1);
}

// ---------------------------------------------------------------------------
// Kernel 3: gx GEMM.  gx[m][g*50+jw] packs units (2jw,2jw+1) of gate g, bf16.
// m = b*CT + t (local to the window being computed).
// ---------------------------------------------------------------------------
__global__ __launch_bounds__(256, 2)
void gx_gemm0(const u32* __restrict__ seq, const float* __restrict__ w_ih,
              const float* __restrict__ b_ih, u32* __restrict__ gxW,
              int c0, int ctl, int CT)
{
    __shared__ float wl[10000];
    const int g    = blockIdx.x % 3;
    const int tile = blockIdx.x / 3;
    const int tid  = threadIdx.x;

    for (int i = tid; i < 10000; i += 256)
        wl[(i % 100) * 100 + (i / 100)] = w_ih[g * 10000 + i];   // transpose
    __syncthreads();

    const int m = tile * 256 + tid;              // 0 .. 128*CT-1
    const int b = m >> ctl;
    const int t = m & (CT - 1);
    const uint2* sr2 = (const uint2*)(seq + ((size_t)b * 1024 + c0 + t) * 50);

    float acc[100];
    const float4* bi4 = (const float4*)(b_ih + g * 100);
#pragma unroll
    for (int j4 = 0; j4 < 25; ++j4) {
        const float4 bv = bi4[j4];
        acc[j4*4+0] = bv.x; acc[j4*4+1] = bv.y; acc[j4*4+2] = bv.z; acc[j4*4+3] = bv.w;
    }

    for (int kk = 0; kk < 25; ++kk) {
        const uint2 up = sr2[kk];
        const float xs[4] = { bflo(up.x), bfhi(up.x), bflo(up.y), bfhi(up.y) };
#pragma unroll
        for (int q = 0; q < 4; ++q) {
            const float* wrow = &wl[(kk * 4 + q) * 100];
            const float xq = xs[q];
#pragma unroll
            for (int j4 = 0; j4 < 25; ++j4) {
                const float4 w4 = *(const float4*)(wrow + j4 * 4);
                acc[j4*4+0] = fmaf(xq, w4.x, acc[j4*4+0]);
                acc[j4*4+1] = fmaf(xq, w4.y, acc[j4*4+1]);
                acc[j4*4+2] = fmaf(xq, w4.z, acc[j4*4+2]);
                acc[j4*4+3] = fmaf(xq, w4.w, acc[j4*4+3]);
            }
        }
    }

    u32* og = gxW + (size_t)m * 150 + g * 50;
#pragma unroll
    for (int i = 0; i < 50; ++i) og[i] = packbf(acc[2*i], acc[2*i+1]);
}

// ---------------------------------------------------------------------------
// Kernel 4 (v12): GRU recurrence, 1 sample/block, 256 threads (4 waves).
// EXACTLY v5's geometry (our best verified: 566 us) -- thread pair (2j,2j+1)
// owns unit j, k-parity halves, ONE barrier/step, single shfl_xor(1) combine,
// padded double-buffered h, distance-2 gx prefetch -- with the per-thread
// W_hh slice stored BF16-PACKED: 78 u32 registers instead of 156 f32.
//
// Why: v5's alloc was 120 VGPR vs ~185 needed -> ~65 floats spilled, ~16
// scratch b128 reloads/thread/step = the ~600cyc gap to the issue floor.
// Six rounds showed the allocator never grants >120 here and AGPRs are not
// legal VALU operands on gfx950 (v11's failure).  So shrink the need under
// the grant: packed weights bring total need to ~114 regs -> no spill.
// Unpack is 2 bit-ops per pair (u<<16 / u&0xffff0000), fp32 FMA unchanged,
// h stays fp32.  Weight rounding uses the same RNE packbf as the rest of
// the pipeline (seq/gx are already bf16).
// ---------------------------------------------------------------------------
__global__ __launch_bounds__(256, 1)
void gru_v12(const u32* __restrict__ gxR, size_t sampStride,
             const float* __restrict__ w_hh, const float* __restrict__ b_hh,
             float* __restrict__ hg, const float* __restrict__ fc1_w,
             const float* __restrict__ fc1_b, float* __restrict__ out,
             int first, int last, int CT)
{
    __shared__ float hb[2][104];        // double-buffered h, [100..103] = 0

    const int tid  = threadIdx.x;
    const int samp = blockIdx.x;
    const int j    = tid >> 1;          // unit 0..127 (meaningful for j<100)
    const int p    = tid & 1;           // k-half parity
    const int hi   = j & 1;             // which bf16 half of the gx word
    const int jc   = (j < 100) ? j : 99;   // clamp so ALL loads are valid

    // ---- weights: 13 float4-groups x 3 gates, each group = 2 packed u32 ----
#define WDECL(g) u32 g##0a, g##0b, g##1a, g##1b, g##2a, g##2b, g##3a, g##3b,  \
                     g##4a, g##4b, g##5a, g##5b, g##6a, g##6b, g##7a, g##7b,  \
                     g##8a, g##8b, g##9a, g##9b, g##10a, g##10b, g##11a,      \
                     g##11b, g##12a, g##12b
    WDECL(wr); WDECL(wz); WDECL(wn);
#undef WDECL
    {
        const float* r0 = w_hh + (size_t)jc * 100;
#define WLOAD(i)                                                              \
        {                                                                     \
            const int   q  = 2 * (i) + p;                                     \
            const int   qc = (q < 25) ? q : 24;                               \
            const float mm = (q < 25) ? 1.f : 0.f;                            \
            float4 v;                                                         \
            v = *(const float4*)(r0 + 4 * qc);                                \
            wr##i##a = packbf(v.x * mm, v.y * mm);                            \
            wr##i##b = packbf(v.z * mm, v.w * mm);                            \
            v = *(const float4*)(r0 + 10000 + 4 * qc);                        \
            wz##i##a = packbf(v.x * mm, v.y * mm);                            \
            wz##i##b = packbf(v.z * mm, v.w * mm);                            \
            v = *(const float4*)(r0 + 20000 + 4 * qc);                        \
            wn##i##a = packbf(v.x * mm, v.y * mm);                            \
            wn##i##b = packbf(v.z * mm, v.w * mm);                            \
        }
        WLOAD(0) WLOAD(1) WLOAD(2) WLOAD(3) WLOAD(4) WLOAD(5) WLOAD(6)
        WLOAD(7) WLOAD(8) WLOAD(9) WLOAD(10) WLOAD(11) WLOAD(12)
#undef WLOAD
    }

    const float bhr = b_hh[jc];
    const float bhz = b_hh[100 + jc];
    const float bhn = b_hh[200 + jc];
    float hreg = first ? 0.f : hg[samp * 100 + jc];

    if (tid < 200 && p == 0) hb[0][j] = hreg;
    if (tid >= 100 && tid < 104) { hb[0][tid] = 0.f; hb[1][tid] = 0.f; }
    __syncthreads();

    // gx prefetch, distance 2 (a-regs: even t, b-regs: odd t); clamped base so
    // inactive threads load valid memory.
    const int w50 = ((tid >> 2) < 50) ? (tid >> 2) : 49;
    const u32* gp = gxR + (size_t)samp * sampStride + w50;
    u32 a0 = gp[0],   a1 = gp[50],  a2 = gp[100];        // t = 0
    u32 b0 = gp[150], b1 = gp[200], b2 = gp[250];        // t = 1

    int cur = 0;

#define SG(i)                                                                 \
    {                                                                         \
        const float4 hv = *(const float4*)(hc + 8 * (i));                     \
        const f2 h01 = {hv.x, hv.y}, h23 = {hv.z, hv.w};                      \
        const f2 wra = {bflo(wr##i##a), bfhi(wr##i##a)};                      \
        const f2 wrb = {bflo(wr##i##b), bfhi(wr##i##b)};                      \
        ar0 += wra * h01;  ar1 += wrb * h23;                                  \
        const f2 wza = {bflo(wz##i##a), bfhi(wz##i##a)};                      \
        const f2 wzb = {bflo(wz##i##b), bfhi(wz##i##b)};                      \
        az0 += wza * h01;  az1 += wzb * h23;                                  \
        const f2 wna = {bflo(wn##i##a), bfhi(wn##i##a)};                      \
        const f2 wnb = {bflo(wn##i##b), bfhi(wn##i##b)};                      \
        an0 += wna * h01;  an1 += wnb * h23;                                  \
    }

#define GRU_STEP(T, X0, X1, X2)                                               \
    {                                                                         \
        const float* hc = &hb[cur][4 * p];                                    \
        f2 ar0 = {0.f,0.f}, ar1 = {0.f,0.f};                                  \
        f2 az0 = {0.f,0.f}, az1 = {0.f,0.f};                                  \
        f2 an0 = {0.f,0.f}, an1 = {0.f,0.f};                                  \
        SG(0) SG(1) SG(2) SG(3) SG(4) SG(5) SG(6)                             \
        SG(7) SG(8) SG(9) SG(10) SG(11) SG(12)                                \
        const u32 c0 = X0, c1 = X1, c2 = X2;                                  \
        if ((T) + 2 < CT) {                                                   \
            const u32* q2 = gp + (size_t)((T) + 2) * 150;                     \
            X0 = q2[0]; X1 = q2[50]; X2 = q2[100];                            \
        }                                                                     \
        float sr = (ar0.x + ar0.y) + (ar1.x + ar1.y);                         \
        float sz = (az0.x + az0.y) + (az1.x + az1.y);                         \
        float sn = (an0.x + an0.y) + (an1.x + an1.y);                         \
        sr += __shfl_xor(sr, 1);                                              \
        sz += __shfl_xor(sz, 1);                                              \
        sn += __shfl_xor(sn, 1);                                              \
        const float gxr = hi ? bfhi(c0) : bflo(c0);                           \
        const float gxz = hi ? bfhi(c1) : bflo(c1);                           \
        const float gxn = hi ? bfhi(c2) : bflo(c2);                           \
        const float rg  = sigm(gxr + sr + bhr);                               \
        const float zg  = sigm(gxz + sz + bhz);                               \
        const float ng  = tanh_fast(gxn + rg * (sn + bhn));                   \
        hreg = (1.f - zg) * ng + zg * hreg;                                   \
        if (tid < 200 && p == 0) hb[cur ^ 1][j] = hreg;                       \
        __syncthreads();                                                      \
        cur ^= 1;                                                             \
    }

    for (int t = 0; t < CT; t += 2) {
        GRU_STEP(t,     a0, a1, a2);
        GRU_STEP(t + 1, b0, b1, b2);
    }
#undef GRU_STEP
#undef SG

    if (tid < 200 && p == 0) hg[samp * 100 + j] = hreg;
    if (last && tid < 100) {
        const float* hc = hb[cur];
        const float4* fw = (const float4*)(fc1_w + (size_t)tid * 100);
        float s0 = 0.f, s1 = 0.f, s2 = 0.f, s3 = 0.f;
#pragma unroll
        for (int kk = 0; kk < 25; ++kk) {
            const float4 wv = fw[kk];
            const float4 hv = *(const float4*)(hc + kk * 4);
            s0 = fmaf(wv.x, hv.x, s0);
            s1 = fmaf(wv.y, hv.y, s1);
            s2 = fmaf(wv.z, hv.z, s2);
            s3 = fmaf(wv.w, hv.w, s3);
        }
        const float s = (s0 + s1) + (s2 + s3) + fc1_b[tid];
        out[samp * 100 + tid] = fmaxf(s, 0.f);
    }
}

// ---------------------------------------------------------------------------
extern "C" void kernel_launch(void* const* d_in, const int* in_sizes, int n_in,
                              void* d_out, int out_size, void* d_ws, size_t ws_size,
                              hipStream_t stream)
{
    const int*   neighbors = (const int*)  d_in[0];
    const int*   adj_row   = (const int*)  d_in[1];
    const int*   adj_col   = (const int*)  d_in[2];
    const float* adj_val   = (const float*)d_in[3];
    const float* emb       = (const float*)d_in[4];
    const float* gcn_w     = (const float*)d_in[5];
    const float* gcn_b     = (const float*)d_in[6];
    const float* w_ih      = (const float*)d_in[7];
    const float* w_hh      = (const float*)d_in[8];
    const float* b_ih      = (const float*)d_in[9];
    const float* b_hh      = (const float*)d_in[10];
    const float* fc1_w     = (const float*)d_in[11];
    const float* fc1_b     = (const float*)d_in[12];
    float* out = (float*)d_out;

    char* ws = (char*)d_ws;
    const size_t seq_bytes     = (size_t)128 * 1024 * 50 * 4;    // 26,214,400
    const size_t hg_bytes      = 128 * 100 * 4;                  // 51,200
    const size_t support_bytes = (size_t)128 * 1024 * 50 * 4;    // 26,214,400
    const size_t offs_bytes    = (size_t)128 * 1025 * 4;         // 524,800

    u32*   seq = (u32*)ws;
    float* hg  = (float*)(ws + seq_bytes);
    char*  rest = ws + seq_bytes + hg_bytes;
    const size_t rest_avail = ws_size - seq_bytes - hg_bytes;

    // Phase 1 (both modes): support + CSR live in `rest` (43.5 MB), all dead
    // before any gx is written over the same region.
    u32*  support = (u32*)rest;
    int*  offs    = (int*)(rest + support_bytes);
    int2* csr     = (int2*)(rest + support_bytes + offs_bytes);

    gcn_kernel<<<512, 256, 0, stream>>>(neighbors, emb, gcn_w, support);
    csr_build<<<128, 256, 0, stream>>>(adj_row, adj_col, adj_val, offs, csr);
    spmm_agg<<<dim3(205, 128), 256, 0, stream>>>(offs, csr, support, gcn_b, seq);

    const size_t gx_full = (size_t)128 * 1024 * 150 * 4;         // 78,643,200
    u32* gx = (u32*)rest;

    if (rest_avail >= gx_full) {
        // full-window: one GEMM dispatch, one 1024-step GRU dispatch
        gx_gemm0<<<1536, 256, 0, stream>>>(seq, w_ih, b_ih, gx, 0, 10, 1024);
        gru_v12<<<128, 256, 0, stream>>>(gx, (size_t)1024 * 150, w_hh, b_hh, hg,
                                         fc1_w, fc1_b, out, 1, 1, 1024);
    } else {
        // chunked fallback
        int CT = 512, ctl = 9;
        while (CT > 8 && (size_t)128 * CT * 150 * 4 > rest_avail) { CT >>= 1; --ctl; }
        const int nch = 1024 / CT;
        for (int c = 0; c < nch; ++c) {
            gx_gemm0<<<3 * (128 * CT / 256), 256, 0, stream>>>(seq, w_ih, b_ih, gx,
                                                               c * CT, ctl, CT);
            gru_v12<<<128, 256, 0, stream>>>(gx, (size_t)CT * 150, w_hh, b_hh, hg,
                                             fc1_w, fc1_b, out,
                                             (c == 0) ? 1 : 0, (c == nch - 1) ? 1 : 0, CT);
        }
    }
}